// Round 13
// baseline (162.695 us; speedup 1.0000x reference)
//
#include <hip/hip_runtime.h>

namespace {

constexpr int L = 2048, Bb = 2, E = 1024, H = 16, D = 64;
constexpr int M = L * Bb;              // 4096 rows (l*B + b)
constexpr int CHK = 64, NC = L / CHK;  // 32 chunks of 64
constexpr int BH = Bb * H;             // 32
constexpr int STSZ = 65 * 64;          // S^T (64x64) + ksum row, per chunk
constexpr float EPS = 1e-4f;
constexpr size_t ASZ = (size_t)M * E;  // elements per activation tensor
constexpr size_t WSZ = (size_t)E * E;  // elements per weight

using bf16 = __bf16;
typedef __attribute__((ext_vector_type(8))) __bf16 bf16x8;
typedef __attribute__((ext_vector_type(4))) __bf16 bf16x4;
typedef __attribute__((ext_vector_type(4))) float f32x4;
typedef __attribute__((ext_vector_type(4))) int i32x4;
typedef __attribute__((ext_vector_type(4))) char char4_t;

#define GLDS16(ldsdst, gsrc)                                      \
  __builtin_amdgcn_global_load_lds(                               \
      (const __attribute__((address_space(1))) void*)(gsrc),      \
      (__attribute__((address_space(3))) void*)(ldsdst), 16, 0, 0)

#define BARRIER_NODRAIN()                      \
  do {                                         \
    asm volatile("" ::: "memory");             \
    __builtin_amdgcn_s_barrier();              \
    asm volatile("" ::: "memory");             \
  } while (0)

__device__ __forceinline__ void split2(float v, bf16& h, bf16& l) {
  h = (bf16)v;
  l = (bf16)(v - (float)h);
}

// element-index XOR swizzle for 64-col bf16 LDS tiles (attn kernels)
__device__ __forceinline__ int SWZ(int e) { return e ^ (((e >> 6) & 7) << 3); }

// ---- per-row dual-digit i8 quant of one 1024-elem row per wave ----
__device__ __forceinline__ void quant_row(const float* __restrict__ src,
                                          signed char* __restrict__ hp,
                                          signed char* __restrict__ lp,
                                          float* __restrict__ sdst, int lane) {
  float4 vv[4];
  float m = 0.f;
#pragma unroll
  for (int j = 0; j < 4; ++j) {
    vv[j] = reinterpret_cast<const float4*>(src)[j * 64 + lane];
    m = fmaxf(m, fmaxf(fmaxf(fabsf(vv[j].x), fabsf(vv[j].y)),
                       fmaxf(fabsf(vv[j].z), fabsf(vv[j].w))));
  }
#pragma unroll
  for (int off = 32; off; off >>= 1) m = fmaxf(m, __shfl_xor(m, off));
  const float s1 = fmaxf(m, 1e-20f) * (1.f / 127.f);
  const float inv1 = 1.f / s1, inv2 = 254.f / s1;
#pragma unroll
  for (int j = 0; j < 4; ++j) {
    const float a[4] = {vv[j].x, vv[j].y, vv[j].z, vv[j].w};
    char4_t hc, lc;
#pragma unroll
    for (int e = 0; e < 4; ++e) {
      const float h = rintf(a[e] * inv1);
      const float r2 = fmaf(-h, s1, a[e]);
      hc[e] = (signed char)(int)h;
      lc[e] = (signed char)(int)rintf(r2 * inv2);
    }
    *reinterpret_cast<char4_t*>(hp + (j * 64 + lane) * 4) = hc;
    *reinterpret_cast<char4_t*>(lp + (j * 64 + lane) * 4) = lc;
  }
  if (lane == 0) *sdst = s1;
}

// ---- quantize q,k,v inputs (3x4096 rows) + all 4 weights (4x1024 rows) ----
__launch_bounds__(256)
__global__ void quant_rows(const float* __restrict__ q, const float* __restrict__ k,
                           const float* __restrict__ v, const float* __restrict__ qw,
                           const float* __restrict__ kw, const float* __restrict__ vw,
                           const float* __restrict__ ow,
                           signed char* __restrict__ Aq, signed char* __restrict__ Wq,
                           float* __restrict__ rsA, float* __restrict__ wrs) {
  const int wv = threadIdx.x >> 6, lane = threadIdx.x & 63;
  int rg = blockIdx.x * 4 + wv;
  const float* src;
  signed char *hp, *lp;
  float* sdst;
  if (rg < 3 * M) {
    const int z = rg >> 12, r = rg & (M - 1);
    src = ((z == 0) ? q : (z == 1) ? k : v) + (size_t)r * E;
    hp = Aq + (size_t)z * 2 * ASZ + (size_t)r * E;
    lp = hp + ASZ;
    sdst = rsA + z * M + r;
  } else {
    rg -= 3 * M;
    const int z = rg >> 10, r = rg & (E - 1);
    src = ((z == 0) ? qw : (z == 1) ? kw : (z == 2) ? vw : ow) + (size_t)r * E;
    hp = Wq + (size_t)z * 2 * WSZ + (size_t)r * E;
    lp = hp + WSZ;
    sdst = wrs + z * E + r;
  }
  quant_row(src, hp, lp, sdst, lane);
}

// ---- quantize the attention output O (4096 rows) ----
__launch_bounds__(256)
__global__ void quantO_rows(const float* __restrict__ o, signed char* __restrict__ Oh,
                            signed char* __restrict__ Ol, float* __restrict__ ors) {
  const int wv = threadIdx.x >> 6, lane = threadIdx.x & 63;
  const int r = blockIdx.x * 4 + wv;
  quant_row(o + (size_t)r * E, Oh + (size_t)r * E, Ol + (size_t)r * E, ors + r, lane);
}

// ------------- QKV dual-digit i8 GEMM, 128x64 tile; B direct from L2 -------------
// One dispatch, 3x512 blocks; z=bid>>9 selects {q,k,v}; rope iff z<2;
// writes split bf16 hi/lo planes in (b,h,n,d) layout. Scales per A-row / W-row.
// A staged via global_load_lds (4/iter); B fragments register-double-buffered
// straight from global (8 loads/iter; L2-resident) -> LDS traffic cut 1/3.
constexpr int GBM = 128, GBN = 64, GBK = 64, NIT = E / GBK;  // 16 K-iters

__launch_bounds__(256, 3)
__global__ void gemm_qkv(const signed char* __restrict__ Abase,
                         const signed char* __restrict__ Wbase,
                         const float* __restrict__ b0, const float* __restrict__ b1,
                         const float* __restrict__ b2, bf16* __restrict__ Pbase,
                         const float* __restrict__ rsA, const float* __restrict__ wrs) {
  __shared__ __align__(16) signed char sA[2][2][GBM * GBK];  // 32KB
  const int tid = threadIdx.x;
  int bid = blockIdx.x;
  const int z = bid >> 9;
  bid &= 511;
  const int wg = (bid & 7) * 64 + (bid >> 3);   // XCD-aware bijective swizzle
  const int row0 = (wg >> 4) * GBM, col0 = (wg & 15) * GBN;
  const signed char* Ah = Abase + (size_t)z * 2 * ASZ;
  const signed char* Al = Ah + ASZ;
  const signed char* Wh = Wbase + (size_t)z * 2 * WSZ;
  const signed char* Wl = Wh + WSZ;
  const float* bias = (z == 0) ? b0 : ((z == 1) ? b1 : b2);
  const float* rs = rsA + z * M;
  const float* ws = wrs + z * E;
  const bool rope = (z < 2);

  const int lane = tid & 63, wid = tid >> 6;
  const int wr = wid >> 1, wc = wid & 1;       // 2x2 waves; wave tile 64x32
  const int fr = lane & 15, kg = lane >> 4;    // fragment row, k-granule (16B)
  i32x4 accH[4][2] = {};
  i32x4 accX[4][2] = {};

  const int lin = tid * 16;                              // byte offset in plane
  const int ar0 = tid >> 2;                              // rows 0..63
  const int acs = (((tid & 3) ^ ((tid >> 3) & 3)) * 16); // swizzled col (i8 elems)
  // B fragment base rows (uniform per lane within quarter-wave groups)
  const size_t brow0 = (size_t)(col0 + wc * 32 + fr) * E + kg * 16;
  const size_t brow1 = (size_t)(col0 + wc * 32 + 16 + fr) * E + kg * 16;

#define STAGE(b_, kt_)                                                                \
  do {                                                                                \
    GLDS16(&sA[b_][0][lin],        Ah + (size_t)(row0 + ar0) * E + (kt_) + acs);      \
    GLDS16(&sA[b_][0][lin + 4096], Ah + (size_t)(row0 + ar0 + 64) * E + (kt_) + acs); \
    GLDS16(&sA[b_][1][lin],        Al + (size_t)(row0 + ar0) * E + (kt_) + acs);      \
    GLDS16(&sA[b_][1][lin + 4096], Al + (size_t)(row0 + ar0 + 64) * E + (kt_) + acs); \
  } while (0)

#define BLOAD(bh_, bl_, kt_)                                                       \
  do {                                                                             \
    bh_[0] = *reinterpret_cast<const i32x4*>(Wh + brow0 + (kt_));                  \
    bh_[1] = *reinterpret_cast<const i32x4*>(Wh + brow1 + (kt_));                  \
    bl_[0] = *reinterpret_cast<const i32x4*>(Wl + brow0 + (kt_));                  \
    bl_[1] = *reinterpret_cast<const i32x4*>(Wl + brow1 + (kt_));                  \
  } while (0)

  i32x4 b0h[2], b0l[2], b1h[2], b1l[2];
  STAGE(0, 0);
  BLOAD(b0h, b0l, 0);
  const int sxa = (fr >> 1) & 3;

  auto kiter = [&](int t, i32x4 (&bch)[2], i32x4 (&bcl)[2],
                   i32x4 (&bnh)[2], i32x4 (&bnl)[2]) {
    const int cur = t & 1;
    if (t + 1 < NIT) {
      STAGE(cur ^ 1, (t + 1) * GBK);
      BLOAD(bnh, bnl, (t + 1) * GBK);
      asm volatile("s_waitcnt vmcnt(12)" ::: "memory");  // tile t's 12 landed
    } else {
      asm volatile("s_waitcnt vmcnt(0)" ::: "memory");
    }
    BARRIER_NODRAIN();

    i32x4 ah[4], al4[4];
#pragma unroll
    for (int m = 0; m < 4; ++m) {
      const int off = (wr * 64 + m * 16 + fr) * GBK + ((kg ^ sxa) * 16);
      ah[m]  = *reinterpret_cast<const i32x4*>(&sA[cur][0][off]);
      al4[m] = *reinterpret_cast<const i32x4*>(&sA[cur][1][off]);
    }
#pragma unroll
    for (int m = 0; m < 4; ++m)
#pragma unroll
      for (int n = 0; n < 2; ++n) {
        accH[m][n] = __builtin_amdgcn_mfma_i32_16x16x64_i8(ah[m], bch[n], accH[m][n], 0, 0, 0);
        accX[m][n] = __builtin_amdgcn_mfma_i32_16x16x64_i8(ah[m], bcl[n], accX[m][n], 0, 0, 0);
        accX[m][n] = __builtin_amdgcn_mfma_i32_16x16x64_i8(al4[m], bch[n], accX[m][n], 0, 0, 0);
      }
    BARRIER_NODRAIN();
  };

  for (int t = 0; t < NIT; t += 2) {
    kiter(t, b0h, b0l, b1h, b1l);
    kiter(t + 1, b1h, b1l, b0h, b0l);
  }
#undef STAGE
#undef BLOAD

  bf16* Ph = Pbase + (size_t)z * 2 * ASZ;

  float rsv[4][4];
#pragma unroll
  for (int m = 0; m < 4; ++m)
#pragma unroll
    for (int i = 0; i < 4; ++i)
      rsv[m][i] = rs[row0 + wr * 64 + m * 16 + kg * 4 + i];
  float wsv[2];
#pragma unroll
  for (int nn = 0; nn < 2; ++nn) wsv[nn] = ws[col0 + wc * 32 + nn * 16 + fr];

  // epilogue: C/D frag layout col=lane&15, row=(lane>>4)*4+i
#pragma unroll
  for (int m = 0; m < 4; ++m) {
    const int rbase = row0 + wr * 64 + m * 16 + kg * 4;
#pragma unroll
    for (int nn = 0; nn < 2; ++nn) {
      const int c = col0 + wc * 32 + nn * 16 + fr;
      const float bia = bias[c];
      float cs0 = 0.f, sn0 = 0.f, cs1 = 0.f, sn1 = 0.f;
      if (rope) {
        const float theta = expf(-(float)((c & 63) >> 1) * 0.2878231366242557f);
        const int n0 = rbase >> 1;             // rbase multiple of 4
        sincosf((float)n0 * theta, &sn0, &cs0);
        sincosf((float)(n0 + 1) * theta, &sn1, &cs1);
      }
#pragma unroll
      for (int i = 0; i < 4; ++i) {
        const float s11 = rsv[m][i] * wsv[nn];
        float v = fmaf((float)accX[m][nn][i], s11 * (1.f / 254.f),
                       fmaf((float)accH[m][nn][i], s11, bia));
        if (rope) {
          v = fmaxf(v, 0.f);
          const float p = __shfl_xor(v, 1);    // rope partner: col c^1, same row
          const float csv = (i < 2) ? cs0 : cs1;
          const float snv = (i < 2) ? sn0 : sn1;
          v = (c & 1) ? fmaf(p, snv, v * csv) : fmaf(-p, snv, v * csv);
        }
        const int r = rbase + i;
        const int nseq = r >> 1, b = r & 1;    // B = 2
        const int hh = c >> 6, dd = c & 63;    // D = 64
        const size_t idx = (((size_t)(b * H + hh)) * L + nseq) * D + dd;
        bf16 h, l;
        split2(v, h, l);
        Ph[idx] = h;
        Ph[ASZ + idx] = l;
      }
    }
  }
}

// ------------- output projection dual-digit i8 GEMM, 128x64 tile; B direct -------------
__launch_bounds__(256, 3)
__global__ void gemm_o(const signed char* __restrict__ Ah, const signed char* __restrict__ Al,
                       const signed char* __restrict__ Wh, const signed char* __restrict__ Wl,
                       const float* __restrict__ bias, float* __restrict__ Cf32,
                       const float* __restrict__ ors, const float* __restrict__ ws) {
  __shared__ __align__(16) signed char sA[2][2][GBM * GBK];  // 32KB
  const int tid = threadIdx.x;
  const int bid = blockIdx.x;
  const int wg = (bid & 7) * 64 + (bid >> 3);
  const int row0 = (wg >> 4) * GBM, col0 = (wg & 15) * GBN;
  const int lane = tid & 63, wid = tid >> 6;
  const int wr = wid >> 1, wc = wid & 1;
  const int fr = lane & 15, kg = lane >> 4;
  i32x4 accH[4][2] = {};
  i32x4 accX[4][2] = {};

  const int lin = tid * 16;
  const int ar0 = tid >> 2;
  const int acs = (((tid & 3) ^ ((tid >> 3) & 3)) * 16);
  const size_t brow0 = (size_t)(col0 + wc * 32 + fr) * E + kg * 16;
  const size_t brow1 = (size_t)(col0 + wc * 32 + 16 + fr) * E + kg * 16;

#define STAGE(b_, kt_)                                                                \
  do {                                                                                \
    GLDS16(&sA[b_][0][lin],        Ah + (size_t)(row0 + ar0) * E + (kt_) + acs);      \
    GLDS16(&sA[b_][0][lin + 4096], Ah + (size_t)(row0 + ar0 + 64) * E + (kt_) + acs); \
    GLDS16(&sA[b_][1][lin],        Al + (size_t)(row0 + ar0) * E + (kt_) + acs);      \
    GLDS16(&sA[b_][1][lin + 4096], Al + (size_t)(row0 + ar0 + 64) * E + (kt_) + acs); \
  } while (0)

#define BLOAD(bh_, bl_, kt_)                                                       \
  do {                                                                             \
    bh_[0] = *reinterpret_cast<const i32x4*>(Wh + brow0 + (kt_));                  \
    bh_[1] = *reinterpret_cast<const i32x4*>(Wh + brow1 + (kt_));                  \
    bl_[0] = *reinterpret_cast<const i32x4*>(Wl + brow0 + (kt_));                  \
    bl_[1] = *reinterpret_cast<const i32x4*>(Wl + brow1 + (kt_));                  \
  } while (0)

  i32x4 b0h[2], b0l[2], b1h[2], b1l[2];
  STAGE(0, 0);
  BLOAD(b0h, b0l, 0);
  const int sxa = (fr >> 1) & 3;

  auto kiter = [&](int t, i32x4 (&bch)[2], i32x4 (&bcl)[2],
                   i32x4 (&bnh)[2], i32x4 (&bnl)[2]) {
    const int cur = t & 1;
    if (t + 1 < NIT) {
      STAGE(cur ^ 1, (t + 1) * GBK);
      BLOAD(bnh, bnl, (t + 1) * GBK);
      asm volatile("s_waitcnt vmcnt(12)" ::: "memory");
    } else {
      asm volatile("s_waitcnt vmcnt(0)" ::: "memory");
    }
    BARRIER_NODRAIN();

    i32x4 ah[4], al4[4];
#pragma unroll
    for (int m = 0; m < 4; ++m) {
      const int off = (wr * 64 + m * 16 + fr) * GBK + ((kg ^ sxa) * 16);
      ah[m]  = *reinterpret_cast<const i32x4*>(&sA[cur][0][off]);
      al4[m] = *reinterpret_cast<const i32x4*>(&sA[cur][1][off]);
    }
#pragma unroll
    for (int m = 0; m < 4; ++m)
#pragma unroll
      for (int n = 0; n < 2; ++n) {
        accH[m][n] = __builtin_amdgcn_mfma_i32_16x16x64_i8(ah[m], bch[n], accH[m][n], 0, 0, 0);
        accX[m][n] = __builtin_amdgcn_mfma_i32_16x16x64_i8(ah[m], bcl[n], accX[m][n], 0, 0, 0);
        accX[m][n] = __builtin_amdgcn_mfma_i32_16x16x64_i8(al4[m], bch[n], accX[m][n], 0, 0, 0);
      }
    BARRIER_NODRAIN();
  };

  for (int t = 0; t < NIT; t += 2) {
    kiter(t, b0h, b0l, b1h, b1l);
    kiter(t + 1, b1h, b1l, b0h, b0l);
  }
#undef STAGE
#undef BLOAD

  float rsv[4][4];
#pragma unroll
  for (int m = 0; m < 4; ++m)
#pragma unroll
    for (int i = 0; i < 4; ++i)
      rsv[m][i] = ors[row0 + wr * 64 + m * 16 + kg * 4 + i];
  float wsv[2];
#pragma unroll
  for (int nn = 0; nn < 2; ++nn) wsv[nn] = ws[col0 + wc * 32 + nn * 16 + fr];

#pragma unroll
  for (int m = 0; m < 4; ++m) {
    const int rbase = row0 + wr * 64 + m * 16 + kg * 4;
#pragma unroll
    for (int nn = 0; nn < 2; ++nn) {
      const int c = col0 + wc * 32 + nn * 16 + fr;
      const float bia = bias[c];
#pragma unroll
      for (int i = 0; i < 4; ++i) {
        const float s11 = rsv[m][i] * wsv[nn];
        const float v = fmaf((float)accX[m][nn][i], s11 * (1.f / 254.f),
                             fmaf((float)accH[m][nn][i], s11, bia));
        Cf32[(size_t)(rbase + i) * E + c] = v;
      }
    }
  }
}

// ---- pass 1 (MFMA): per-chunk S^T_ext = V^T_ext(80x64) . K(64x64) -> st[65][64] ----
__launch_bounds__(256)
__global__ void attn_state(const bf16* __restrict__ Kh, const bf16* __restrict__ Kl,
                           const bf16* __restrict__ Vh, const bf16* __restrict__ Vl,
                           float* __restrict__ st) {
  __shared__ bf16 sVh[80 * 64], sVl[80 * 64];  // V^T_ext (row 64 = ones)
  __shared__ bf16 sKh[64 * 64], sKl[64 * 64];  // K^T (rows d, cols m)
  const int bx = blockIdx.x;
  const int bh = bx / NC, c = bx % NC;
  const int tid = threadIdx.x;
  const size_t gbase = ((size_t)bh * L + (size_t)c * CHK) * D;

  for (int i = tid; i < 512; i += 256) {
    const int m = i >> 3, c8 = (i & 7) * 8;
    const size_t g = gbase + (size_t)m * 64 + c8;
    const bf16x8 kh8 = *reinterpret_cast<const bf16x8*>(Kh + g);
    const bf16x8 kl8 = *reinterpret_cast<const bf16x8*>(Kl + g);
    const bf16x8 vh8 = *reinterpret_cast<const bf16x8*>(Vh + g);
    const bf16x8 vl8 = *reinterpret_cast<const bf16x8*>(Vl + g);
#pragma unroll
    for (int j = 0; j < 8; ++j) {
      sKh[SWZ((c8 + j) * 64 + m)] = kh8[j];
      sKl[SWZ((c8 + j) * 64 + m)] = kl8[j];
      sVh[SWZ((c8 + j) * 64 + m)] = vh8[j];
      sVl[SWZ((c8 + j) * 64 + m)] = vl8[j];
    }
  }
  for (int i = tid; i < 16 * 64; i += 256) {
    const int r = 64 + (i >> 6), cc = i & 63;
    sVh[SWZ(r * 64 + cc)] = (r == 64) ? (bf16)1.0f : (bf16)0.0f;
    sVl[SWZ(r * 64 + cc)] = (bf16)0.0f;
  }
  __syncthreads();

  const int w = tid >> 6, lane = tid & 63;
  const int fr = lane & 15, kg = lane >> 4;
  f32x4 acc[5] = {};
#pragma unroll
  for (int ks = 0; ks < 2; ++ks) {
    const int boff = SWZ((w * 16 + fr) * 64 + ks * 32 + kg * 8);
    const bf16x8 bh_ = *reinterpret_cast<const bf16x8*>(&sKh[boff]);
    const bf16x8 bl_ = *reinterpret_cast<const bf16x8*>(&sKl[boff]);
#pragma unroll
    for (int rt = 0; rt < 5; ++rt) {
      const int aoff = SWZ((rt * 16 + fr) * 64 + ks * 32 + kg * 8);
      const bf16x8 ah = *reinterpret_cast<const bf16x8*>(&sVh[aoff]);
      const bf16x8 al = *reinterpret_cast<const bf16x8*>(&sVl[aoff]);
      acc[rt] = __builtin_amdgcn_mfma_f32_16x16x32_bf16(ah, bh_, acc[rt], 0, 0, 0);
      acc[rt] = __builtin_amdgcn_mfma_f32_16x16x32_bf16(ah, bl_, acc[rt], 0, 0, 0);
      acc[rt] = __builtin_amdgcn_mfma_f32_16x16x32_bf16(al, bh_, acc[rt], 0, 0, 0);
    }
  }
  float* stp = st + (size_t)bx * STSZ;
#pragma unroll
  for (int rt = 0; rt < 5; ++rt)
#pragma unroll
    for (int i = 0; i < 4; ++i) {
      const int e = rt * 16 + kg * 4 + i;
      if (e < 65) stp[e * 64 + w * 16 + fr] = acc[rt][i];
    }
}

// ---------------- pass 2: exclusive prefix scan over chunks ----------------
__launch_bounds__(256)
__global__ void attn_scan(float* __restrict__ st) {
  const int bh = blockIdx.x;
  const int j = blockIdx.y * 256 + threadIdx.x;
  if (j >= STSZ) return;
  float run = 0.f;
  for (int c = 0; c < NC; ++c) {
    const size_t o = ((size_t)(bh * NC + c)) * STSZ + j;
    const float v = st[o];
    st[o] = run;
    run += v;
  }
}

// ---- pass 3 (MFMA fused): W=QK^T causal; O = W~ V + Q S_excl; rowsum via ones/ksum ----
__launch_bounds__(256)
__global__ void attn_out(const bf16* __restrict__ Qh, const bf16* __restrict__ Ql,
                         const bf16* __restrict__ Kh, const bf16* __restrict__ Kl,
                         const bf16* __restrict__ Vh, const bf16* __restrict__ Vl,
                         const float* __restrict__ st, float* __restrict__ Ot) {
  __shared__ bf16 sQh[64 * 64], sQl[64 * 64];
  __shared__ bf16 sKWh[64 * 64], sKWl[64 * 64];  // K (phase1) then W~ (phase2)
  __shared__ bf16 sVh[80 * 64], sVl[80 * 64];    // V^T_ext (row64 = ones)
  __shared__ bf16 sSh[80 * 64], sSl[80 * 64];    // S^T_ext (row64 = ksum_excl)
  const int bx = blockIdx.x;
  const int bh = bx / NC, c = bx % NC;
  const int tid = threadIdx.x;
  const size_t gbase = ((size_t)bh * L + (size_t)c * CHK) * D;

  for (int i = tid; i < 512; i += 256) {
    const int m = i >> 3, c8 = (i & 7) * 8;
    const size_t g = gbase + (size_t)m * 64 + c8;
    const bf16x8 qh8 = *reinterpret_cast<const bf16x8*>(Qh + g);
    const bf16x8 ql8 = *reinterpret_cast<const bf16x8*>(Ql + g);
    const bf16x8 kh8 = *reinterpret_cast<const bf16x8*>(Kh + g);
    const bf16x8 kl8 = *reinterpret_cast<const bf16x8*>(Kl + g);
    const bf16x8 vh8 = *reinterpret_cast<const bf16x8*>(Vh + g);
    const bf16x8 vl8 = *reinterpret_cast<const bf16x8*>(Vl + g);
    const int rm = SWZ(m * 64 + c8);               // row-uniform swizzle, 8-aligned
    *reinterpret_cast<bf16x8*>(&sQh[rm]) = qh8;
    *reinterpret_cast<bf16x8*>(&sQl[rm]) = ql8;
    *reinterpret_cast<bf16x8*>(&sKWh[rm]) = kh8;
    *reinterpret_cast<bf16x8*>(&sKWl[rm]) = kl8;
#pragma unroll
    for (int j = 0; j < 8; ++j) {
      sVh[SWZ((c8 + j) * 64 + m)] = vh8[j];
      sVl[SWZ((c8 + j) * 64 + m)] = vl8[j];
    }
  }
  const float* stp = st + (size_t)(bh * NC + c) * STSZ;
  for (int i = tid; i < 1040; i += 256) {
    const float4 sv = *reinterpret_cast<const float4*>(stp + i * 4);
    const float sa[4] = {sv.x, sv.y, sv.z, sv.w};
    bf16x4 h4, l4;
#pragma unroll
    for (int j = 0; j < 4; ++j) {
      bf16 th, tl;
      split2(sa[j], th, tl);
      h4[j] = th; l4[j] = tl;
    }
    *reinterpret_cast<bf16x4*>(&sSh[SWZ(i * 4)]) = h4;
    *reinterpret_cast<bf16x4*>(&sSl[SWZ(i * 4)]) = l4;
  }
  for (int i = tid; i < 16 * 64; i += 256) {
    const int r = 64 + (i >> 6), cc = i & 63;
    sVh[SWZ(r * 64 + cc)] = (r == 64) ? (bf16)1.0f : (bf16)0.0f;
    sVl[SWZ(r * 64 + cc)] = (bf16)0.0f;
    if (r > 64) { sSh[SWZ(r * 64 + cc)] = (bf16)0.0f; sSl[SWZ(r * 64 + cc)] = (bf16)0.0f; }
  }
  __syncthreads();

  const int w = tid >> 6, lane = tid & 63;
  const int fr = lane & 15, kg = lane >> 4;
  f32x4 Wacc[4] = {};
  f32x4 Oacc[5] = {};

#pragma unroll
  for (int ks = 0; ks < 2; ++ks) {
    const int aoff = SWZ((w * 16 + fr) * 64 + ks * 32 + kg * 8);
    const bf16x8 ah = *reinterpret_cast<const bf16x8*>(&sQh[aoff]);
    const bf16x8 al = *reinterpret_cast<const bf16x8*>(&sQl[aoff]);
    for (int t = 0; t <= w; ++t) {
      const int boff = SWZ((t * 16 + fr) * 64 + ks * 32 + kg * 8);
      const bf16x8 bh_ = *reinterpret_cast<const bf16x8*>(&sKWh[boff]);
      const bf16x8 bl_ = *reinterpret_cast<const bf16x8*>(&sKWl[boff]);
      Wacc[t] = __builtin_amdgcn_mfma_f32_16x16x32_bf16(ah, bh_, Wacc[t], 0, 0, 0);
      Wacc[t] = __builtin_amdgcn_mfma_f32_16x16x32_bf16(ah, bl_, Wacc[t], 0, 0, 0);
      Wacc[t] = __builtin_amdgcn_mfma_f32_16x16x32_bf16(al, bh_, Wacc[t], 0, 0, 0);
    }
#pragma unroll
    for (int ct = 0; ct < 5; ++ct) {
      const int soff = SWZ((ct * 16 + fr) * 64 + ks * 32 + kg * 8);
      const bf16x8 sh = *reinterpret_cast<const bf16x8*>(&sSh[soff]);
      const bf16x8 sl = *reinterpret_cast<const bf16x8*>(&sSl[soff]);
      Oacc[ct] = __builtin_amdgcn_mfma_f32_16x16x32_bf16(ah, sh, Oacc[ct], 0, 0, 0);
      Oacc[ct] = __builtin_amdgcn_mfma_f32_16x16x32_bf16(ah, sl, Oacc[ct], 0, 0, 0);
      Oacc[ct] = __builtin_amdgcn_mfma_f32_16x16x32_bf16(al, sh, Oacc[ct], 0, 0, 0);
    }
  }
  __syncthreads();

#pragma unroll
  for (int t = 0; t < 4; ++t)
#pragma unroll
    for (int i = 0; i < 4; ++i) {
      const int n_loc = w * 16 + kg * 4 + i;
      const int m_loc = t * 16 + fr;
      const float v = (m_loc <= n_loc) ? Wacc[t][i] : 0.f;
      bf16 h, l;
      split2(v, h, l);
      sKWh[SWZ(n_loc * 64 + m_loc)] = h;
      sKWl[SWZ(n_loc * 64 + m_loc)] = l;
    }
  __syncthreads();

  const int kmax = (w < 2) ? 1 : 2;
  for (int ks = 0; ks < kmax; ++ks) {
    const int aoff = SWZ((w * 16 + fr) * 64 + ks * 32 + kg * 8);
    const bf16x8 ah = *reinterpret_cast<const bf16x8*>(&sKWh[aoff]);
    const bf16x8 al = *reinterpret_cast<const bf16x8*>(&sKWl[aoff]);
#pragma unroll
    for (int ct = 0; ct < 5; ++ct) {
      const int boff = SWZ((ct * 16 + fr) * 64 + ks * 32 + kg * 8);
      const bf16x8 bh_ = *reinterpret_cast<const bf16x8*>(&sVh[boff]);
      const bf16x8 bl_ = *reinterpret_cast<const bf16x8*>(&sVl[boff]);
      Oacc[ct] = __builtin_amdgcn_mfma_f32_16x16x32_bf16(ah, bh_, Oacc[ct], 0, 0, 0);
      Oacc[ct] = __builtin_amdgcn_mfma_f32_16x16x32_bf16(ah, bl_, Oacc[ct], 0, 0, 0);
      Oacc[ct] = __builtin_amdgcn_mfma_f32_16x16x32_bf16(al, bh_, Oacc[ct], 0, 0, 0);
    }
  }

  float inv[4];
#pragma unroll
  for (int i = 0; i < 4; ++i) {
    float r = Oacc[4][i];
    r += __shfl_xor(r, 1);
    r += __shfl_xor(r, 2);
    r += __shfl_xor(r, 4);
    r += __shfl_xor(r, 8);
    inv[i] = 1.f / fmaxf(r, EPS);
  }

  const int b = bh >> 4, hh = bh & 15;
#pragma unroll
  for (int i = 0; i < 4; ++i) {
    const int nglob = c * CHK + w * 16 + kg * 4 + i;
    const size_t rowb = ((size_t)nglob * Bb + b) * E + (size_t)hh * D;
#pragma unroll
    for (int t = 0; t < 4; ++t) Ot[rowb + t * 16 + fr] = Oacc[t][i] * inv[i];
  }
}

} // namespace

extern "C" void kernel_launch(void* const* d_in, const int* in_sizes, int n_in,
                              void* d_out, int out_size, void* d_ws, size_t ws_size,
                              hipStream_t stream) {
  (void)in_sizes; (void)n_in; (void)out_size; (void)ws_size;
  const float* query = (const float*)d_in[0];
  const float* key_  = (const float*)d_in[1];
  const float* value = (const float*)d_in[2];
  const float* q_w   = (const float*)d_in[3];
  const float* q_b   = (const float*)d_in[4];
  const float* k_w   = (const float*)d_in[5];
  const float* k_b   = (const float*)d_in[6];
  const float* v_w   = (const float*)d_in[7];
  const float* v_b   = (const float*)d_in[8];
  const float* out_w = (const float*)d_in[9];
  const float* out_b = (const float*)d_in[10];
  float* out = (float*)d_out;

  constexpr size_t MB = 1u << 20;
  char* wsb = (char*)d_ws;
  bf16* P = (bf16*)wsb;                            // [0,48MB): 6 bf16 planes
  float* o_f32 = (float*)(wsb + 48 * MB);          // [48,64MB)
  float* st = (float*)(wsb + 64 * MB);             // [64,82MB)
  signed char* Aq = (signed char*)(wsb + 82 * MB); // [82,106MB): 3x2 i8 act planes
  signed char* Wq = (signed char*)(wsb + 106 * MB);// [106,114MB): 4x2 i8 wt planes
  signed char* Ohq = (signed char*)(wsb + 114 * MB);
  signed char* Olq = Ohq + ASZ;                    // [114,122MB)
  float* rsA = (float*)(wsb + 122 * MB);           // [3][4096] A row scales
  float* wrs = rsA + 3 * M;                        // [4][1024] W row scales
  float* ors = wrs + 4 * E;                        // [4096] O row scales

  // 1. per-row quantize q,k,v inputs + all 4 weights (scales computed in-kernel)
  hipLaunchKernelGGL(quant_rows, dim3((3 * M + 4 * E) / 4), dim3(256), 0, stream,
                     query, key_, value, q_w, k_w, v_w, out_w, Aq, Wq, rsA, wrs);
  // 2. three projections, one dispatch (rope for q,k) -> bf16 hi/lo planes
  hipLaunchKernelGGL(gemm_qkv, dim3(3 * 512), dim3(256), 0, stream,
                     Aq, Wq, q_b, k_b, v_b, P, rsA, wrs);
  // 3-5. attention
  hipLaunchKernelGGL(attn_state, dim3(BH * NC), dim3(256), 0, stream,
                     P + 2 * ASZ, P + 3 * ASZ, P + 4 * ASZ, P + 5 * ASZ, st);
  hipLaunchKernelGGL(attn_scan, dim3(BH, (STSZ + 255) / 256), dim3(256), 0, stream, st);
  hipLaunchKernelGGL(attn_out, dim3(BH * NC), dim3(256), 0, stream,
                     P, P + ASZ, P + 2 * ASZ, P + 3 * ASZ, P + 4 * ASZ, P + 5 * ASZ,
                     st, o_f32);
  // 6. per-row quantize O
  hipLaunchKernelGGL(quantO_rows, dim3(M / 4), dim3(256), 0, stream, o_f32, Ohq, Olq, ors);
  // 7. output projection
  hipLaunchKernelGGL(gemm_o, dim3(512), dim3(256), 0, stream,
                     Ohq, Olq, Wq + 3 * 2 * WSZ, Wq + 3 * 2 * WSZ + WSZ,
                     out_b, out, ors, wrs + 3 * E);
}

// Round 14
// 139.227 us; speedup vs baseline: 1.1686x; 1.1686x over previous
//
#include <hip/hip_runtime.h>

namespace {

constexpr int L = 2048, Bb = 2, E = 1024, H = 16, D = 64;
constexpr int M = L * Bb;              // 4096 rows (l*B + b)
constexpr int CHK = 64, NC = L / CHK;  // 32 chunks of 64
constexpr int BH = Bb * H;             // 32
constexpr int STSZ = 65 * 64;          // S^T (64x64) + ksum row, per chunk
constexpr float EPS = 1e-4f;
constexpr size_t ASZ = (size_t)M * E;  // elements per activation tensor
constexpr size_t WSZ = (size_t)E * E;  // elements per weight
constexpr int NBQ = (3 * M + 4 * E) / 4;  // 4096 quant blocks

using bf16 = __bf16;
typedef __attribute__((ext_vector_type(8))) __bf16 bf16x8;
typedef __attribute__((ext_vector_type(4))) __bf16 bf16x4;
typedef __attribute__((ext_vector_type(4))) float f32x4;
typedef __attribute__((ext_vector_type(4))) int i32x4;
typedef __attribute__((ext_vector_type(4))) char char4_t;

#define GLDS16(ldsdst, gsrc)                                      \
  __builtin_amdgcn_global_load_lds(                               \
      (const __attribute__((address_space(1))) void*)(gsrc),      \
      (__attribute__((address_space(3))) void*)(ldsdst), 16, 0, 0)

#define BARRIER_NODRAIN()                      \
  do {                                         \
    asm volatile("" ::: "memory");             \
    __builtin_amdgcn_s_barrier();              \
    asm volatile("" ::: "memory");             \
  } while (0)

__device__ __forceinline__ void split2(float v, bf16& h, bf16& l) {
  h = (bf16)v;
  l = (bf16)(v - (float)h);
}

// element-index XOR swizzle for 64-col bf16 LDS tiles (attn kernels)
__device__ __forceinline__ int SWZ(int e) { return e ^ (((e >> 6) & 7) << 3); }

// ---- per-row dual-digit i8 quant of one 1024-elem row per wave ----
__device__ __forceinline__ void quant_row(const float* __restrict__ src,
                                          signed char* __restrict__ hp,
                                          signed char* __restrict__ lp,
                                          float* __restrict__ sdst, int lane) {
  float4 vv[4];
  float m = 0.f;
#pragma unroll
  for (int j = 0; j < 4; ++j) {
    vv[j] = reinterpret_cast<const float4*>(src)[j * 64 + lane];
    m = fmaxf(m, fmaxf(fmaxf(fabsf(vv[j].x), fabsf(vv[j].y)),
                       fmaxf(fabsf(vv[j].z), fabsf(vv[j].w))));
  }
#pragma unroll
  for (int off = 32; off; off >>= 1) m = fmaxf(m, __shfl_xor(m, off));
  const float s1 = fmaxf(m, 1e-20f) * (1.f / 127.f);
  const float inv1 = 1.f / s1, inv2 = 254.f / s1;
#pragma unroll
  for (int j = 0; j < 4; ++j) {
    const float a[4] = {vv[j].x, vv[j].y, vv[j].z, vv[j].w};
    char4_t hc, lc;
#pragma unroll
    for (int e = 0; e < 4; ++e) {
      const float h = rintf(a[e] * inv1);
      const float r2 = fmaf(-h, s1, a[e]);
      hc[e] = (signed char)(int)h;
      lc[e] = (signed char)(int)rintf(r2 * inv2);
    }
    *reinterpret_cast<char4_t*>(hp + (j * 64 + lane) * 4) = hc;
    *reinterpret_cast<char4_t*>(lp + (j * 64 + lane) * 4) = lc;
  }
  if (lane == 0) *sdst = s1;
}

// ---- quantize q,k,v inputs + all 4 weights; extra blocks build the RoPE LUT ----
__launch_bounds__(256)
__global__ void quant_rows(const float* __restrict__ q, const float* __restrict__ k,
                           const float* __restrict__ v, const float* __restrict__ qw,
                           const float* __restrict__ kw, const float* __restrict__ vw,
                           const float* __restrict__ ow,
                           signed char* __restrict__ Aq, signed char* __restrict__ Wq,
                           float* __restrict__ rsA, float* __restrict__ wrs,
                           float2* __restrict__ ropetab) {
  if (blockIdx.x >= NBQ) {
    // RoPE LUT: tab[n*32+i] = (cos, sin)(n * theta_i), theta_i = 10000^(-i/32)
    const int idx = (blockIdx.x - NBQ) * 256 + threadIdx.x;  // 65536 entries
    const int n = idx >> 5, i = idx & 31;
    const float theta = expf(-(float)i * 0.2878231366242557f);
    float s, c;
    sincosf((float)n * theta, &s, &c);
    ropetab[idx] = make_float2(c, s);
    return;
  }
  const int wv = threadIdx.x >> 6, lane = threadIdx.x & 63;
  int rg = blockIdx.x * 4 + wv;
  const float* src;
  signed char *hp, *lp;
  float* sdst;
  if (rg < 3 * M) {
    const int z = rg >> 12, r = rg & (M - 1);
    src = ((z == 0) ? q : (z == 1) ? k : v) + (size_t)r * E;
    hp = Aq + (size_t)z * 2 * ASZ + (size_t)r * E;
    lp = hp + ASZ;
    sdst = rsA + z * M + r;
  } else {
    rg -= 3 * M;
    const int z = rg >> 10, r = rg & (E - 1);
    src = ((z == 0) ? qw : (z == 1) ? kw : (z == 2) ? vw : ow) + (size_t)r * E;
    hp = Wq + (size_t)z * 2 * WSZ + (size_t)r * E;
    lp = hp + WSZ;
    sdst = wrs + z * E + r;
  }
  quant_row(src, hp, lp, sdst, lane);
}

// ---- quantize the attention output O (4096 rows) ----
__launch_bounds__(256)
__global__ void quantO_rows(const float* __restrict__ o, signed char* __restrict__ Oh,
                            signed char* __restrict__ Ol, float* __restrict__ ors) {
  const int wv = threadIdx.x >> 6, lane = threadIdx.x & 63;
  const int r = blockIdx.x * 4 + wv;
  quant_row(o + (size_t)r * E, Oh + (size_t)r * E, Ol + (size_t)r * E, ors + r, lane);
}

// ------------- QKV dual-digit i8 GEMM, 128x64 tile (R12-proven) -------------
// One dispatch, 3x512 blocks; z=bid>>9 selects {q,k,v}; rope iff z<2 (via LUT);
// writes split bf16 hi/lo planes in (b,h,n,d) layout. Scales per A-row / W-row.
constexpr int GBM = 128, GBN = 64, GBK = 64, NIT = E / GBK;  // 16 K-iters

__launch_bounds__(256, 3)
__global__ void gemm_qkv(const signed char* __restrict__ Abase,
                         const signed char* __restrict__ Wbase,
                         const float* __restrict__ b0, const float* __restrict__ b1,
                         const float* __restrict__ b2, bf16* __restrict__ Pbase,
                         const float* __restrict__ rsA, const float* __restrict__ wrs,
                         const float2* __restrict__ ropetab) {
  __shared__ __align__(16) signed char sA[2][2][GBM * GBK];  // 32KB
  __shared__ __align__(16) signed char sB[2][2][GBN * GBK];  // 16KB
  const int tid = threadIdx.x;
  int bid = blockIdx.x;
  const int z = bid >> 9;
  bid &= 511;
  const int wg = (bid & 7) * 64 + (bid >> 3);   // XCD-aware bijective swizzle
  const int row0 = (wg >> 4) * GBM, col0 = (wg & 15) * GBN;
  const signed char* Ah = Abase + (size_t)z * 2 * ASZ;
  const signed char* Al = Ah + ASZ;
  const signed char* Wh = Wbase + (size_t)z * 2 * WSZ;
  const signed char* Wl = Wh + WSZ;
  const float* bias = (z == 0) ? b0 : ((z == 1) ? b1 : b2);
  const float* rs = rsA + z * M;
  const float* ws = wrs + z * E;
  const bool rope = (z < 2);

  const int lane = tid & 63, wid = tid >> 6;
  const int wr = wid >> 1, wc = wid & 1;       // 2x2 waves; wave tile 64x32
  const int fr = lane & 15, kg = lane >> 4;    // fragment row, k-granule (16B)
  i32x4 accH[4][2] = {};
  i32x4 accX[4][2] = {};

  const int lin = tid * 16;                              // byte offset in plane
  const int ar0 = tid >> 2;                              // rows 0..63
  const int acs = (((tid & 3) ^ ((tid >> 3) & 3)) * 16); // swizzled col (i8 elems)

#define STAGE(b_, kt_)                                                                \
  do {                                                                                \
    GLDS16(&sA[b_][0][lin],        Ah + (size_t)(row0 + ar0) * E + (kt_) + acs);      \
    GLDS16(&sA[b_][0][lin + 4096], Ah + (size_t)(row0 + ar0 + 64) * E + (kt_) + acs); \
    GLDS16(&sA[b_][1][lin],        Al + (size_t)(row0 + ar0) * E + (kt_) + acs);      \
    GLDS16(&sA[b_][1][lin + 4096], Al + (size_t)(row0 + ar0 + 64) * E + (kt_) + acs); \
    GLDS16(&sB[b_][0][lin],        Wh + (size_t)(col0 + ar0) * E + (kt_) + acs);      \
    GLDS16(&sB[b_][1][lin],        Wl + (size_t)(col0 + ar0) * E + (kt_) + acs);      \
  } while (0)

  STAGE(0, 0);
  const int sxa = (fr >> 1) & 3;
  for (int t = 0; t < NIT; ++t) {
    const int cur = t & 1;
    if (t + 1 < NIT) {
      STAGE(cur ^ 1, (t + 1) * GBK);
      asm volatile("s_waitcnt vmcnt(6)" ::: "memory");  // tile t's 6 loads landed
    } else {
      asm volatile("s_waitcnt vmcnt(0)" ::: "memory");
    }
    BARRIER_NODRAIN();

    i32x4 ah[4], al4[4], bh2[2], bl2[2];
#pragma unroll
    for (int m = 0; m < 4; ++m) {
      const int off = (wr * 64 + m * 16 + fr) * GBK + ((kg ^ sxa) * 16);
      ah[m]  = *reinterpret_cast<const i32x4*>(&sA[cur][0][off]);
      al4[m] = *reinterpret_cast<const i32x4*>(&sA[cur][1][off]);
    }
#pragma unroll
    for (int n = 0; n < 2; ++n) {
      const int off = (wc * 32 + n * 16 + fr) * GBK + ((kg ^ sxa) * 16);
      bh2[n] = *reinterpret_cast<const i32x4*>(&sB[cur][0][off]);
      bl2[n] = *reinterpret_cast<const i32x4*>(&sB[cur][1][off]);
    }
#pragma unroll
    for (int m = 0; m < 4; ++m)
#pragma unroll
      for (int n = 0; n < 2; ++n) {
        accH[m][n] = __builtin_amdgcn_mfma_i32_16x16x64_i8(ah[m], bh2[n], accH[m][n], 0, 0, 0);
        accX[m][n] = __builtin_amdgcn_mfma_i32_16x16x64_i8(ah[m], bl2[n], accX[m][n], 0, 0, 0);
        accX[m][n] = __builtin_amdgcn_mfma_i32_16x16x64_i8(al4[m], bh2[n], accX[m][n], 0, 0, 0);
      }
    BARRIER_NODRAIN();
  }
#undef STAGE

  bf16* Ph = Pbase + (size_t)z * 2 * ASZ;

  // per-row / per-col dequant scales
  float rsv[4][4];
#pragma unroll
  for (int m = 0; m < 4; ++m)
#pragma unroll
    for (int i = 0; i < 4; ++i)
      rsv[m][i] = rs[row0 + wr * 64 + m * 16 + kg * 4 + i];
  float wsv[2];
#pragma unroll
  for (int nn = 0; nn < 2; ++nn) wsv[nn] = ws[col0 + wc * 32 + nn * 16 + fr];

  // epilogue: C/D frag layout col=lane&15, row=(lane>>4)*4+i
#pragma unroll
  for (int m = 0; m < 4; ++m) {
    const int rbase = row0 + wr * 64 + m * 16 + kg * 4;
#pragma unroll
    for (int nn = 0; nn < 2; ++nn) {
      const int c = col0 + wc * 32 + nn * 16 + fr;
      const float bia = bias[c];
      float cs0 = 0.f, sn0 = 0.f, cs1 = 0.f, sn1 = 0.f;
      if (rope) {
        const int pi = (c & 63) >> 1;          // pair index within head
        const int n0 = rbase >> 1;             // rbase multiple of 4
        const float2 t0 = ropetab[(n0 << 5) | pi];
        const float2 t1 = ropetab[((n0 + 1) << 5) | pi];
        cs0 = t0.x; sn0 = t0.y;
        cs1 = t1.x; sn1 = t1.y;
      }
#pragma unroll
      for (int i = 0; i < 4; ++i) {
        const float s11 = rsv[m][i] * wsv[nn];
        float v = fmaf((float)accX[m][nn][i], s11 * (1.f / 254.f),
                       fmaf((float)accH[m][nn][i], s11, bia));
        if (rope) {
          v = fmaxf(v, 0.f);
          const float p = __shfl_xor(v, 1);    // rope partner: col c^1, same row
          const float csv = (i < 2) ? cs0 : cs1;
          const float snv = (i < 2) ? sn0 : sn1;
          v = (c & 1) ? fmaf(p, snv, v * csv) : fmaf(-p, snv, v * csv);
        }
        const int r = rbase + i;
        const int nseq = r >> 1, b = r & 1;    // B = 2
        const int hh = c >> 6, dd = c & 63;    // D = 64
        const size_t idx = (((size_t)(b * H + hh)) * L + nseq) * D + dd;
        bf16 h, l;
        split2(v, h, l);
        Ph[idx] = h;
        Ph[ASZ + idx] = l;
      }
    }
  }
}

// ------------- output projection dual-digit i8 GEMM, 128x64 tile -------------
__launch_bounds__(256, 3)
__global__ void gemm_o(const signed char* __restrict__ Ah, const signed char* __restrict__ Al,
                       const signed char* __restrict__ Wh, const signed char* __restrict__ Wl,
                       const float* __restrict__ bias, float* __restrict__ Cf32,
                       const float* __restrict__ ors, const float* __restrict__ ws) {
  __shared__ __align__(16) signed char sA[2][2][GBM * GBK];  // 32KB
  __shared__ __align__(16) signed char sB[2][2][GBN * GBK];  // 16KB
  const int tid = threadIdx.x;
  const int bid = blockIdx.x;
  const int wg = (bid & 7) * 64 + (bid >> 3);
  const int row0 = (wg >> 4) * GBM, col0 = (wg & 15) * GBN;
  const int lane = tid & 63, wid = tid >> 6;
  const int wr = wid >> 1, wc = wid & 1;
  const int fr = lane & 15, kg = lane >> 4;
  i32x4 accH[4][2] = {};
  i32x4 accX[4][2] = {};

  const int lin = tid * 16;
  const int ar0 = tid >> 2;
  const int acs = (((tid & 3) ^ ((tid >> 3) & 3)) * 16);

#define STAGE(b_, kt_)                                                                \
  do {                                                                                \
    GLDS16(&sA[b_][0][lin],        Ah + (size_t)(row0 + ar0) * E + (kt_) + acs);      \
    GLDS16(&sA[b_][0][lin + 4096], Ah + (size_t)(row0 + ar0 + 64) * E + (kt_) + acs); \
    GLDS16(&sA[b_][1][lin],        Al + (size_t)(row0 + ar0) * E + (kt_) + acs);      \
    GLDS16(&sA[b_][1][lin + 4096], Al + (size_t)(row0 + ar0 + 64) * E + (kt_) + acs); \
    GLDS16(&sB[b_][0][lin],        Wh + (size_t)(col0 + ar0) * E + (kt_) + acs);      \
    GLDS16(&sB[b_][1][lin],        Wl + (size_t)(col0 + ar0) * E + (kt_) + acs);      \
  } while (0)

  STAGE(0, 0);
  const int sxa = (fr >> 1) & 3;
  for (int t = 0; t < NIT; ++t) {
    const int cur = t & 1;
    if (t + 1 < NIT) {
      STAGE(cur ^ 1, (t + 1) * GBK);
      asm volatile("s_waitcnt vmcnt(6)" ::: "memory");
    } else {
      asm volatile("s_waitcnt vmcnt(0)" ::: "memory");
    }
    BARRIER_NODRAIN();

    i32x4 ah[4], al4[4], bh2[2], bl2[2];
#pragma unroll
    for (int m = 0; m < 4; ++m) {
      const int off = (wr * 64 + m * 16 + fr) * GBK + ((kg ^ sxa) * 16);
      ah[m]  = *reinterpret_cast<const i32x4*>(&sA[cur][0][off]);
      al4[m] = *reinterpret_cast<const i32x4*>(&sA[cur][1][off]);
    }
#pragma unroll
    for (int n = 0; n < 2; ++n) {
      const int off = (wc * 32 + n * 16 + fr) * GBK + ((kg ^ sxa) * 16);
      bh2[n] = *reinterpret_cast<const i32x4*>(&sB[cur][0][off]);
      bl2[n] = *reinterpret_cast<const i32x4*>(&sB[cur][1][off]);
    }
#pragma unroll
    for (int m = 0; m < 4; ++m)
#pragma unroll
      for (int n = 0; n < 2; ++n) {
        accH[m][n] = __builtin_amdgcn_mfma_i32_16x16x64_i8(ah[m], bh2[n], accH[m][n], 0, 0, 0);
        accX[m][n] = __builtin_amdgcn_mfma_i32_16x16x64_i8(ah[m], bl2[n], accX[m][n], 0, 0, 0);
        accX[m][n] = __builtin_amdgcn_mfma_i32_16x16x64_i8(al4[m], bh2[n], accX[m][n], 0, 0, 0);
      }
    BARRIER_NODRAIN();
  }
#undef STAGE

  float rsv[4][4];
#pragma unroll
  for (int m = 0; m < 4; ++m)
#pragma unroll
    for (int i = 0; i < 4; ++i)
      rsv[m][i] = ors[row0 + wr * 64 + m * 16 + kg * 4 + i];
  float wsv[2];
#pragma unroll
  for (int nn = 0; nn < 2; ++nn) wsv[nn] = ws[col0 + wc * 32 + nn * 16 + fr];

#pragma unroll
  for (int m = 0; m < 4; ++m) {
    const int rbase = row0 + wr * 64 + m * 16 + kg * 4;
#pragma unroll
    for (int nn = 0; nn < 2; ++nn) {
      const int c = col0 + wc * 32 + nn * 16 + fr;
      const float bia = bias[c];
#pragma unroll
      for (int i = 0; i < 4; ++i) {
        const float s11 = rsv[m][i] * wsv[nn];
        const float v = fmaf((float)accX[m][nn][i], s11 * (1.f / 254.f),
                             fmaf((float)accH[m][nn][i], s11, bia));
        Cf32[(size_t)(rbase + i) * E + c] = v;
      }
    }
  }
}

// ---- pass 1 (MFMA): per-chunk S^T_ext = V^T_ext(80x64) . K(64x64) -> st[65][64] ----
__launch_bounds__(256)
__global__ void attn_state(const bf16* __restrict__ Kh, const bf16* __restrict__ Kl,
                           const bf16* __restrict__ Vh, const bf16* __restrict__ Vl,
                           float* __restrict__ st) {
  __shared__ bf16 sVh[80 * 64], sVl[80 * 64];  // V^T_ext (row 64 = ones)
  __shared__ bf16 sKh[64 * 64], sKl[64 * 64];  // K^T (rows d, cols m)
  const int bx = blockIdx.x;
  const int bh = bx / NC, c = bx % NC;
  const int tid = threadIdx.x;
  const size_t gbase = ((size_t)bh * L + (size_t)c * CHK) * D;

  for (int i = tid; i < 512; i += 256) {
    const int m = i >> 3, c8 = (i & 7) * 8;
    const size_t g = gbase + (size_t)m * 64 + c8;
    const bf16x8 kh8 = *reinterpret_cast<const bf16x8*>(Kh + g);
    const bf16x8 kl8 = *reinterpret_cast<const bf16x8*>(Kl + g);
    const bf16x8 vh8 = *reinterpret_cast<const bf16x8*>(Vh + g);
    const bf16x8 vl8 = *reinterpret_cast<const bf16x8*>(Vl + g);
#pragma unroll
    for (int j = 0; j < 8; ++j) {
      sKh[SWZ((c8 + j) * 64 + m)] = kh8[j];
      sKl[SWZ((c8 + j) * 64 + m)] = kl8[j];
      sVh[SWZ((c8 + j) * 64 + m)] = vh8[j];
      sVl[SWZ((c8 + j) * 64 + m)] = vl8[j];
    }
  }
  for (int i = tid; i < 16 * 64; i += 256) {
    const int r = 64 + (i >> 6), cc = i & 63;
    sVh[SWZ(r * 64 + cc)] = (r == 64) ? (bf16)1.0f : (bf16)0.0f;
    sVl[SWZ(r * 64 + cc)] = (bf16)0.0f;
  }
  __syncthreads();

  const int w = tid >> 6, lane = tid & 63;
  const int fr = lane & 15, kg = lane >> 4;
  f32x4 acc[5] = {};
#pragma unroll
  for (int ks = 0; ks < 2; ++ks) {
    const int boff = SWZ((w * 16 + fr) * 64 + ks * 32 + kg * 8);
    const bf16x8 bh_ = *reinterpret_cast<const bf16x8*>(&sKh[boff]);
    const bf16x8 bl_ = *reinterpret_cast<const bf16x8*>(&sKl[boff]);
#pragma unroll
    for (int rt = 0; rt < 5; ++rt) {
      const int aoff = SWZ((rt * 16 + fr) * 64 + ks * 32 + kg * 8);
      const bf16x8 ah = *reinterpret_cast<const bf16x8*>(&sVh[aoff]);
      const bf16x8 al = *reinterpret_cast<const bf16x8*>(&sVl[aoff]);
      acc[rt] = __builtin_amdgcn_mfma_f32_16x16x32_bf16(ah, bh_, acc[rt], 0, 0, 0);
      acc[rt] = __builtin_amdgcn_mfma_f32_16x16x32_bf16(ah, bl_, acc[rt], 0, 0, 0);
      acc[rt] = __builtin_amdgcn_mfma_f32_16x16x32_bf16(al, bh_, acc[rt], 0, 0, 0);
    }
  }
  float* stp = st + (size_t)bx * STSZ;
#pragma unroll
  for (int rt = 0; rt < 5; ++rt)
#pragma unroll
    for (int i = 0; i < 4; ++i) {
      const int e = rt * 16 + kg * 4 + i;
      if (e < 65) stp[e * 64 + w * 16 + fr] = acc[rt][i];
    }
}

// ---------------- pass 2: exclusive prefix scan over chunks ----------------
__launch_bounds__(256)
__global__ void attn_scan(float* __restrict__ st) {
  const int bh = blockIdx.x;
  const int j = blockIdx.y * 256 + threadIdx.x;
  if (j >= STSZ) return;
  float run = 0.f;
  for (int c = 0; c < NC; ++c) {
    const size_t o = ((size_t)(bh * NC + c)) * STSZ + j;
    const float v = st[o];
    st[o] = run;
    run += v;
  }
}

// ---- pass 3 (MFMA fused): W=QK^T causal; O = W~ V + Q S_excl; rowsum via ones/ksum ----
__launch_bounds__(256)
__global__ void attn_out(const bf16* __restrict__ Qh, const bf16* __restrict__ Ql,
                         const bf16* __restrict__ Kh, const bf16* __restrict__ Kl,
                         const bf16* __restrict__ Vh, const bf16* __restrict__ Vl,
                         const float* __restrict__ st, float* __restrict__ Ot) {
  __shared__ bf16 sQh[64 * 64], sQl[64 * 64];
  __shared__ bf16 sKWh[64 * 64], sKWl[64 * 64];  // K (phase1) then W~ (phase2)
  __shared__ bf16 sVh[80 * 64], sVl[80 * 64];    // V^T_ext (row64 = ones)
  __shared__ bf16 sSh[80 * 64], sSl[80 * 64];    // S^T_ext (row64 = ksum_excl)
  const int bx = blockIdx.x;
  const int bh = bx / NC, c = bx % NC;
  const int tid = threadIdx.x;
  const size_t gbase = ((size_t)bh * L + (size_t)c * CHK) * D;

  for (int i = tid; i < 512; i += 256) {
    const int m = i >> 3, c8 = (i & 7) * 8;
    const size_t g = gbase + (size_t)m * 64 + c8;
    const bf16x8 qh8 = *reinterpret_cast<const bf16x8*>(Qh + g);
    const bf16x8 ql8 = *reinterpret_cast<const bf16x8*>(Ql + g);
    const bf16x8 kh8 = *reinterpret_cast<const bf16x8*>(Kh + g);
    const bf16x8 kl8 = *reinterpret_cast<const bf16x8*>(Kl + g);
    const bf16x8 vh8 = *reinterpret_cast<const bf16x8*>(Vh + g);
    const bf16x8 vl8 = *reinterpret_cast<const bf16x8*>(Vl + g);
    const int rm = SWZ(m * 64 + c8);               // row-uniform swizzle, 8-aligned
    *reinterpret_cast<bf16x8*>(&sQh[rm]) = qh8;
    *reinterpret_cast<bf16x8*>(&sQl[rm]) = ql8;
    *reinterpret_cast<bf16x8*>(&sKWh[rm]) = kh8;
    *reinterpret_cast<bf16x8*>(&sKWl[rm]) = kl8;
#pragma unroll
    for (int j = 0; j < 8; ++j) {
      sVh[SWZ((c8 + j) * 64 + m)] = vh8[j];
      sVl[SWZ((c8 + j) * 64 + m)] = vl8[j];
    }
  }
  const float* stp = st + (size_t)(bh * NC + c) * STSZ;
  for (int i = tid; i < 1040; i += 256) {
    const float4 sv = *reinterpret_cast<const float4*>(stp + i * 4);
    const float sa[4] = {sv.x, sv.y, sv.z, sv.w};
    bf16x4 h4, l4;
#pragma unroll
    for (int j = 0; j < 4; ++j) {
      bf16 th, tl;
      split2(sa[j], th, tl);
      h4[j] = th; l4[j] = tl;
    }
    *reinterpret_cast<bf16x4*>(&sSh[SWZ(i * 4)]) = h4;
    *reinterpret_cast<bf16x4*>(&sSl[SWZ(i * 4)]) = l4;
  }
  for (int i = tid; i < 16 * 64; i += 256) {
    const int r = 64 + (i >> 6), cc = i & 63;
    sVh[SWZ(r * 64 + cc)] = (r == 64) ? (bf16)1.0f : (bf16)0.0f;
    sVl[SWZ(r * 64 + cc)] = (bf16)0.0f;
    if (r > 64) { sSh[SWZ(r * 64 + cc)] = (bf16)0.0f; sSl[SWZ(r * 64 + cc)] = (bf16)0.0f; }
  }
  __syncthreads();

  const int w = tid >> 6, lane = tid & 63;
  const int fr = lane & 15, kg = lane >> 4;
  f32x4 Wacc[4] = {};
  f32x4 Oacc[5] = {};

#pragma unroll
  for (int ks = 0; ks < 2; ++ks) {
    const int aoff = SWZ((w * 16 + fr) * 64 + ks * 32 + kg * 8);
    const bf16x8 ah = *reinterpret_cast<const bf16x8*>(&sQh[aoff]);
    const bf16x8 al = *reinterpret_cast<const bf16x8*>(&sQl[aoff]);
    for (int t = 0; t <= w; ++t) {
      const int boff = SWZ((t * 16 + fr) * 64 + ks * 32 + kg * 8);
      const bf16x8 bh_ = *reinterpret_cast<const bf16x8*>(&sKWh[boff]);
      const bf16x8 bl_ = *reinterpret_cast<const bf16x8*>(&sKWl[boff]);
      Wacc[t] = __builtin_amdgcn_mfma_f32_16x16x32_bf16(ah, bh_, Wacc[t], 0, 0, 0);
      Wacc[t] = __builtin_amdgcn_mfma_f32_16x16x32_bf16(ah, bl_, Wacc[t], 0, 0, 0);
      Wacc[t] = __builtin_amdgcn_mfma_f32_16x16x32_bf16(al, bh_, Wacc[t], 0, 0, 0);
    }
#pragma unroll
    for (int ct = 0; ct < 5; ++ct) {
      const int soff = SWZ((ct * 16 + fr) * 64 + ks * 32 + kg * 8);
      const bf16x8 sh = *reinterpret_cast<const bf16x8*>(&sSh[soff]);
      const bf16x8 sl = *reinterpret_cast<const bf16x8*>(&sSl[soff]);
      Oacc[ct] = __builtin_amdgcn_mfma_f32_16x16x32_bf16(ah, sh, Oacc[ct], 0, 0, 0);
      Oacc[ct] = __builtin_amdgcn_mfma_f32_16x16x32_bf16(ah, sl, Oacc[ct], 0, 0, 0);
      Oacc[ct] = __builtin_amdgcn_mfma_f32_16x16x32_bf16(al, sh, Oacc[ct], 0, 0, 0);
    }
  }
  __syncthreads();

#pragma unroll
  for (int t = 0; t < 4; ++t)
#pragma unroll
    for (int i = 0; i < 4; ++i) {
      const int n_loc = w * 16 + kg * 4 + i;
      const int m_loc = t * 16 + fr;
      const float v = (m_loc <= n_loc) ? Wacc[t][i] : 0.f;
      bf16 h, l;
      split2(v, h, l);
      sKWh[SWZ(n_loc * 64 + m_loc)] = h;
      sKWl[SWZ(n_loc * 64 + m_loc)] = l;
    }
  __syncthreads();

  const int kmax = (w < 2) ? 1 : 2;
  for (int ks = 0; ks < kmax; ++ks) {
    const int aoff = SWZ((w * 16 + fr) * 64 + ks * 32 + kg * 8);
    const bf16x8 ah = *reinterpret_cast<const bf16x8*>(&sKWh[aoff]);
    const bf16x8 al = *reinterpret_cast<const bf16x8*>(&sKWl[aoff]);
#pragma unroll
    for (int ct = 0; ct < 5; ++ct) {
      const int boff = SWZ((ct * 16 + fr) * 64 + ks * 32 + kg * 8);
      const bf16x8 bh_ = *reinterpret_cast<const bf16x8*>(&sVh[boff]);
      const bf16x8 bl_ = *reinterpret_cast<const bf16x8*>(&sVl[boff]);
      Oacc[ct] = __builtin_amdgcn_mfma_f32_16x16x32_bf16(ah, bh_, Oacc[ct], 0, 0, 0);
      Oacc[ct] = __builtin_amdgcn_mfma_f32_16x16x32_bf16(ah, bl_, Oacc[ct], 0, 0, 0);
      Oacc[ct] = __builtin_amdgcn_mfma_f32_16x16x32_bf16(al, bh_, Oacc[ct], 0, 0, 0);
    }
  }

  float inv[4];
#pragma unroll
  for (int i = 0; i < 4; ++i) {
    float r = Oacc[4][i];
    r += __shfl_xor(r, 1);
    r += __shfl_xor(r, 2);
    r += __shfl_xor(r, 4);
    r += __shfl_xor(r, 8);
    inv[i] = 1.f / fmaxf(r, EPS);
  }

  const int b = bh >> 4, hh = bh & 15;
#pragma unroll
  for (int i = 0; i < 4; ++i) {
    const int nglob = c * CHK + w * 16 + kg * 4 + i;
    const size_t rowb = ((size_t)nglob * Bb + b) * E + (size_t)hh * D;
#pragma unroll
    for (int t = 0; t < 4; ++t) Ot[rowb + t * 16 + fr] = Oacc[t][i] * inv[i];
  }
}

} // namespace

extern "C" void kernel_launch(void* const* d_in, const int* in_sizes, int n_in,
                              void* d_out, int out_size, void* d_ws, size_t ws_size,
                              hipStream_t stream) {
  (void)in_sizes; (void)n_in; (void)out_size; (void)ws_size;
  const float* query = (const float*)d_in[0];
  const float* key_  = (const float*)d_in[1];
  const float* value = (const float*)d_in[2];
  const float* q_w   = (const float*)d_in[3];
  const float* q_b   = (const float*)d_in[4];
  const float* k_w   = (const float*)d_in[5];
  const float* k_b   = (const float*)d_in[6];
  const float* v_w   = (const float*)d_in[7];
  const float* v_b   = (const float*)d_in[8];
  const float* out_w = (const float*)d_in[9];
  const float* out_b = (const float*)d_in[10];
  float* out = (float*)d_out;

  constexpr size_t MB = 1u << 20;
  char* wsb = (char*)d_ws;
  bf16* P = (bf16*)wsb;                            // [0,48MB): 6 bf16 planes
  float* o_f32 = (float*)(wsb + 48 * MB);          // [48,64MB)
  float* st = (float*)(wsb + 64 * MB);             // [64,82MB)
  signed char* Aq = (signed char*)(wsb + 82 * MB); // [82,106MB): 3x2 i8 act planes
  signed char* Wq = (signed char*)(wsb + 106 * MB);// [106,114MB): 4x2 i8 wt planes
  signed char* Ohq = (signed char*)(wsb + 114 * MB);
  signed char* Olq = Ohq + ASZ;                    // [114,122MB)
  float* rsA = (float*)(wsb + 122 * MB);           // [3][4096] A row scales
  float* wrs = rsA + 3 * M;                        // [4][1024] W row scales
  float* ors = wrs + 4 * E;                        // [4096] O row scales
  float2* ropetab = (float2*)(wsb + 123 * MB);     // [2048][32] cos/sin LUT

  // 1. per-row quantize inputs+weights; tail blocks build the RoPE LUT
  hipLaunchKernelGGL(quant_rows, dim3(NBQ + 256), dim3(256), 0, stream,
                     query, key_, value, q_w, k_w, v_w, out_w, Aq, Wq, rsA, wrs, ropetab);
  // 2. three projections, one dispatch (rope for q,k via LUT) -> bf16 hi/lo planes
  hipLaunchKernelGGL(gemm_qkv, dim3(3 * 512), dim3(256), 0, stream,
                     Aq, Wq, q_b, k_b, v_b, P, rsA, wrs, ropetab);
  // 3-5. attention
  hipLaunchKernelGGL(attn_state, dim3(BH * NC), dim3(256), 0, stream,
                     P + 2 * ASZ, P + 3 * ASZ, P + 4 * ASZ, P + 5 * ASZ, st);
  hipLaunchKernelGGL(attn_scan, dim3(BH, (STSZ + 255) / 256), dim3(256), 0, stream, st);
  hipLaunchKernelGGL(attn_out, dim3(BH * NC), dim3(256), 0, stream,
                     P, P + ASZ, P + 2 * ASZ, P + 3 * ASZ, P + 4 * ASZ, P + 5 * ASZ,
                     st, o_f32);
  // 6. per-row quantize O
  hipLaunchKernelGGL(quantO_rows, dim3(M / 4), dim3(256), 0, stream, o_f32, Ohq, Olq, ors);
  // 7. output projection
  hipLaunchKernelGGL(gemm_o, dim3(512), dim3(256), 0, stream,
                     Ohq, Olq, Wq + 3 * 2 * WSZ, Wq + 3 * 2 * WSZ + WSZ,
                     out_b, out, ors, wrs + 3 * E);
}